// Round 1
// baseline (2611.902 us; speedup 1.0000x reference)
//
#include <hip/hip_runtime.h>
#include <hip/hip_bf16.h>

#define DEV __device__ __forceinline__

constexpr int N  = 65536;
constexpr int C  = 768;
constexpr int G  = 16;
constexpr int CG = 48;
constexpr int T  = 64;

using bf16 = __hip_bfloat16;

DEV float b2f(bf16 v) { return __bfloat162float(v); }
DEV bf16  f2b(float v) { return __float2bfloat16(v); }

DEV float wredsum(float v) {
#pragma unroll
  for (int o = 32; o > 0; o >>= 1) v += __shfl_xor(v, o, 64);
  return v;
}

// ---------------------------------------------------------------------------
// K1: LayerNorm rows of x -> xn (bf16), accumulate pooled sums (fp32 atomics)
// grid 1024 x 256 threads; each wave handles 16 rows.
// ---------------------------------------------------------------------------
__global__ __launch_bounds__(256) void k_ln(const float* __restrict__ x,
                                            const float* __restrict__ gam,
                                            const float* __restrict__ bet,
                                            bf16* __restrict__ xn,
                                            float* __restrict__ pooled) {
  const int tid = threadIdx.x, wave = tid >> 6, lane = tid & 63;
  float gg[12], bb[12], pool[12];
#pragma unroll
  for (int j = 0; j < 12; j++) { gg[j] = gam[lane + 64 * j]; bb[j] = bet[lane + 64 * j]; pool[j] = 0.f; }
  const int r0 = (blockIdx.x * 4 + wave) * 16;
  for (int r = r0; r < r0 + 16; ++r) {
    const float* xr = x + (size_t)r * C;
    float v[12]; float s = 0.f;
#pragma unroll
    for (int j = 0; j < 12; j++) { v[j] = xr[lane + 64 * j]; s += v[j]; }
    s = wredsum(s);
    const float mu = s * (1.f / C);
    float q = 0.f;
#pragma unroll
    for (int j = 0; j < 12; j++) { float d = v[j] - mu; q += d * d; }
    q = wredsum(q);
    const float rs = rsqrtf(q * (1.f / C) + 1e-5f);
    bf16* xo = xn + (size_t)r * C;
#pragma unroll
    for (int j = 0; j < 12; j++) {
      float y = (v[j] - mu) * rs * gg[j] + bb[j];
      pool[j] += y;
      xo[lane + 64 * j] = f2b(y);
    }
  }
  __shared__ float lp[4][C];
#pragma unroll
  for (int j = 0; j < 12; j++) lp[wave][lane + 64 * j] = pool[j];
  __syncthreads();
  for (int c = tid; c < C; c += 256)
    atomicAdd(&pooled[c], lp[0][c] + lp[1][c] + lp[2][c] + lp[3][c]);
}

// ---------------------------------------------------------------------------
// K2: pooled -> ratio -> num_tokens (1 block)
// ---------------------------------------------------------------------------
__global__ __launch_bounds__(256) void k_pool(const float* __restrict__ pooled,
                                              const float* __restrict__ pw,
                                              const float* __restrict__ pb,
                                              int* __restrict__ ntok) {
  const int tid = threadIdx.x, wave = tid >> 6, lane = tid & 63;
  float a = 0.f;
  for (int c = tid; c < C; c += 256) a += pooled[c] * (1.f / N) * pw[c];
  a = wredsum(a);
  __shared__ float red[4];
  if (lane == 0) red[wave] = a;
  __syncthreads();
  if (tid == 0) {
    float d = red[0] + red[1] + red[2] + red[3] + pb[0];
    float ratio = 1.f / (1.f + expf(-d));
    int nt = (int)floorf(ratio * 64.f);
    nt = nt < 0 ? 0 : (nt > 64 ? 64 : nt);
    *ntok = nt;
  }
}

// ---------------------------------------------------------------------------
// K3: fused grouped conv1 + ReLU + scores GEMM.  Block = 32 rows.
// LDS: xn tile (bf16 32x768), staged weight slice (padded stride 49),
//      h tile (bf16 32x49).  Scores accumulated in registers [8/thread].
// ---------------------------------------------------------------------------
__global__ __launch_bounds__(256) void k_cs(const bf16* __restrict__ xn,
                                            const float* __restrict__ w1,
                                            const float* __restrict__ w2,
                                            float* __restrict__ scores) {
  __shared__ bf16  xs[32 * 768];   // 49152 B
  __shared__ float wst[64 * 49];   // 12544 B (holds w1[g] or w2 slice, padded)
  __shared__ bf16  hs[32 * 49];    // 3136 B
  const int tid = threadIdx.x;
  const int n0 = blockIdx.x * 32;
  {
    const uint4* src = (const uint4*)(xn + (size_t)n0 * C);
    uint4* dst = (uint4*)xs;
#pragma unroll
    for (int k = 0; k < 12; k++) dst[tid + 256 * k] = src[tid + 256 * k];
  }
  float acc[8];
#pragma unroll
  for (int k = 0; k < 8; k++) acc[k] = 0.f;
  const int t0 = (tid >> 5) * 8, srow = tid & 31;

  for (int g = 0; g < G; ++g) {
    __syncthreads();
    // stage w1[g] with +1 pad (kills (16o+i)%32 bank conflict)
    for (int i = tid; i < 2304; i += 256) { int o = i / 48, ii = i - o * 48; wst[o * 49 + ii] = w1[g * 2304 + i]; }
    __syncthreads();
    // h = relu(xn_g @ w1[g]^T)
#pragma unroll
    for (int k = 0; k < 6; k++) {
      int idx = tid + 256 * k; int row = idx / 48; int o = idx - row * 48;
      const bf16* xr = &xs[row * 768 + g * 48];
      const float* wr = &wst[o * 49];
      float a = 0.f;
#pragma unroll
      for (int i = 0; i < 48; i++) a += b2f(xr[i]) * wr[i];
      hs[row * 49 + o] = f2b(a > 0.f ? a : 0.f);
    }
    __syncthreads();
    // stage w2[:, g*48 .. +48]
    for (int i = tid; i < 3072; i += 256) { int t = i / 48, o = i - t * 48; wst[t * 49 + o] = w2[t * 768 + g * 48 + o]; }
    __syncthreads();
    // scores[t,row] += h[row,:] . w2[t,:]
#pragma unroll
    for (int k = 0; k < 8; k++) {
      const float* wr = &wst[(t0 + k) * 49];
      const bf16* hr = &hs[srow * 49];
      float a = acc[k];
#pragma unroll
      for (int o = 0; o < 48; o++) a += b2f(hr[o]) * wr[o];
      acc[k] = a;
    }
  }
#pragma unroll
  for (int k = 0; k < 8; k++) scores[(size_t)(t0 + k) * N + n0 + srow] = acc[k];
}

// ---------------------------------------------------------------------------
// K4: per-(t, segment) online softmax partial stats
// ---------------------------------------------------------------------------
__global__ __launch_bounds__(256) void k_stats(const float* __restrict__ scores,
                                               float2* __restrict__ part) {
  const int t = blockIdx.x >> 3, s = blockIdx.x & 7;
  const float* row = scores + (size_t)t * N + s * 8192;
  float m = -1e30f, l = 0.f;
  for (int i = threadIdx.x; i < 8192; i += 256) {
    float v = row[i];
    if (v > m) { l = l * __expf(m - v) + 1.f; m = v; }
    else       { l += __expf(v - m); }
  }
#pragma unroll
  for (int o = 32; o > 0; o >>= 1) {
    float m2 = __shfl_xor(m, o, 64), l2 = __shfl_xor(l, o, 64);
    float M = fmaxf(m, m2);
    l = l * __expf(m - M) + l2 * __expf(m2 - M); m = M;
  }
  __shared__ float sm[4], sl[4];
  const int wave = threadIdx.x >> 6, lane = threadIdx.x & 63;
  if (lane == 0) { sm[wave] = m; sl[wave] = l; }
  __syncthreads();
  if (threadIdx.x == 0) {
    float M = sm[0], L = sl[0];
    for (int w = 1; w < 4; w++) { float M2 = fmaxf(M, sm[w]); L = L * __expf(M - M2) + sl[w] * __expf(sm[w] - M2); M = M2; }
    part[blockIdx.x] = make_float2(M, L);
  }
}

// K5: merge the 8 segment stats per row
__global__ void k_sfinal(const float2* __restrict__ part, float* __restrict__ Mv,
                         float* __restrict__ Li) {
  int t = threadIdx.x;  // 64 threads
  float M = -1e30f, L = 0.f;
  for (int s = 0; s < 8; s++) {
    float2 p = part[t * 8 + s];
    float M2 = fmaxf(M, p.x);
    L = L * __expf(M - M2) + p.y * __expf(p.x - M2); M = M2;
  }
  Mv[t] = M; Li[t] = 1.f / L;
}

// K6: write selected = exp(s-M)/L, masked rows -> 0
__global__ __launch_bounds__(256) void k_sel(const float* __restrict__ scores,
                                             const float* __restrict__ Mv,
                                             const float* __restrict__ Li,
                                             const int* __restrict__ ntokp,
                                             float* __restrict__ sel) {
  const int t = blockIdx.x >> 3, s = blockIdx.x & 7;
  const size_t base = (size_t)t * N + s * 8192;
  const bool on = t < *ntokp;
  const float m = Mv[t], li = Li[t];
  for (int i = threadIdx.x; i < 8192; i += 256)
    sel[base + i] = on ? __expf(scores[base + i] - m) * li : 0.f;
}

// ---------------------------------------------------------------------------
// K7: out[t,c] = sum_n sel[t,n] * feat[n,c]; feat recomputed per c-tile
// grid (128 n-chunks of 512, 4 c-tiles of 192 = 4 groups).
// fp32 atomics into out_acc[64][768].
// ---------------------------------------------------------------------------
__global__ __launch_bounds__(256) void k_og(const bf16* __restrict__ xn,
                                            const float* __restrict__ wf,
                                            const float* __restrict__ sel,
                                            const int* __restrict__ ntokp,
                                            float* __restrict__ out_acc) {
  __shared__ bf16  wfs[4 * 48 * 49];  // 18816 B (padded stride 49)
  __shared__ bf16  xsb[32 * 192];     // 12288 B
  __shared__ bf16  fs[32 * 196];      // 12544 B
  __shared__ float ps[64 * 32];       // 8192 B
  const int tid = threadIdx.x, wave = tid >> 6, cl = tid & 63;
  const int ct = blockIdx.y, C0 = ct * 192, g0b = ct * 4;
  const int nbase = blockIdx.x * 512;
  const int ntok = *ntokp;
  for (int i = tid; i < 4 * 2304; i += 256) {
    int g = i / 2304, r = i - g * 2304; int o = r / 48, ii = r - o * 48;
    wfs[g * 2352 + o * 49 + ii] = f2b(wf[(size_t)(g0b + g) * 2304 + r]);
  }
  float acc[16][3];
#pragma unroll
  for (int k = 0; k < 16; k++) { acc[k][0] = 0.f; acc[k][1] = 0.f; acc[k][2] = 0.f; }
  const bool wave_on = (wave * 16) < ntok;

  for (int sc = 0; sc < 16; ++sc) {
    const int n0 = nbase + sc * 32;
    __syncthreads();
    {  // stage xn[n0..n0+32, C0..C0+192] (vectorized, 24 uint4 per row)
      uint4* dst = (uint4*)xsb;
#pragma unroll
      for (int k = 0; k < 3; k++) {
        int i = tid + 256 * k; int n = i / 24, q = i - n * 24;
        const uint4* src = (const uint4*)(xn + (size_t)(n0 + n) * C + C0);
        dst[i] = src[q];
      }
    }
    for (int i = tid; i < 2048; i += 256) { int t = i >> 5, n = i & 31; ps[i] = sel[(size_t)t * N + n0 + n]; }
    __syncthreads();
    // feat tile: 32 n x 192 c
#pragma unroll
    for (int k = 0; k < 24; k++) {
      int idx = tid + 256 * k; int n = idx / 192, c = idx - n * 192; int g = c / 48, o = c - g * 48;
      const bf16* xr = &xsb[n * 192 + g * 48];
      const bf16* wr = &wfs[g * 2352 + o * 49];
      float a = 0.f;
#pragma unroll
      for (int i2 = 0; i2 < 48; i2++) a += b2f(xr[i2]) * b2f(wr[i2]);
      fs[n * 196 + c] = f2b(a);
    }
    __syncthreads();
    if (wave_on) {
      for (int n = 0; n < 32; ++n) {
        float f0 = b2f(fs[n * 196 + cl]);
        float f1 = b2f(fs[n * 196 + cl + 64]);
        float f2v = b2f(fs[n * 196 + cl + 128]);
#pragma unroll
        for (int k = 0; k < 16; k++) {
          float p = ps[(wave * 16 + k) * 32 + n];
          acc[k][0] += p * f0; acc[k][1] += p * f1; acc[k][2] += p * f2v;
        }
      }
    }
  }
  if (wave_on) {
#pragma unroll
    for (int k = 0; k < 16; k++) {
      int t = wave * 16 + k;
#pragma unroll
      for (int m = 0; m < 3; m++) atomicAdd(&out_acc[t * C + C0 + cl + 64 * m], acc[k][m]);
    }
  }
}

// K8: final LayerNorm of out rows + mask
__global__ __launch_bounds__(256) void k_ofinal(const float* __restrict__ out_acc,
                                                const float* __restrict__ ng,
                                                const float* __restrict__ nb,
                                                const int* __restrict__ ntokp,
                                                float* __restrict__ outp) {
  const int tid = threadIdx.x, wave = tid >> 6, lane = tid & 63;
  const int ntok = *ntokp;
  for (int t = wave; t < T; t += 4) {
    const float* r = out_acc + t * C;
    float v[12]; float s = 0.f;
#pragma unroll
    for (int j = 0; j < 12; j++) { v[j] = r[lane + 64 * j]; s += v[j]; }
    s = wredsum(s); float mu = s * (1.f / C);
    float q = 0.f;
#pragma unroll
    for (int j = 0; j < 12; j++) { float d = v[j] - mu; q += d * d; }
    q = wredsum(q); float rs = rsqrtf(q * (1.f / C) + 1e-5f);
    float* o = outp + t * C;
#pragma unroll
    for (int j = 0; j < 12; j++) {
      int c = lane + 64 * j;
      float y = (v[j] - mu) * rs * ng[c] + nb[c];
      o[c] = (t < ntok) ? y : 0.f;
    }
  }
}

// ---------------------------------------------------------------------------
extern "C" void kernel_launch(void* const* d_in, const int* in_sizes, int n_in,
                              void* d_out, int out_size, void* d_ws, size_t ws_size,
                              hipStream_t stream) {
  const float* x  = (const float*)d_in[0];
  const float* tg = (const float*)d_in[1];
  const float* tb = (const float*)d_in[2];
  const float* w1 = (const float*)d_in[3];
  const float* w2 = (const float*)d_in[4];
  const float* wf = (const float*)d_in[5];
  const float* pw = (const float*)d_in[6];
  const float* pb = (const float*)d_in[7];
  const float* ng = (const float*)d_in[8];
  const float* nb = (const float*)d_in[9];

  char* ws = (char*)d_ws;
  bf16*   xn     = (bf16*)(ws);                        // 100,663,296 B
  float*  scores = (float*)(ws + 100663296);           // 16,777,216 B
  float*  pooled = (float*)(ws + 117440512);           // 3,072 B
  float2* part   = (float2*)(ws + 117444608);          // 4,096 B
  float*  Mv     = (float*)(ws + 117448704);           // 256 B
  float*  Li     = (float*)(ws + 117448960);           // 256 B
  int*    ntok   = (int*)(ws + 117449216);             // 4 B
  float*  oacc   = (float*)(ws + 117449472);           // 196,608 B

  float* sel  = (float*)d_out;
  float* outp = (float*)d_out + (size_t)T * N;

  hipMemsetAsync(pooled, 0, C * sizeof(float), stream);
  hipMemsetAsync(oacc, 0, T * C * sizeof(float), stream);

  k_ln    <<<1024, 256, 0, stream>>>(x, tg, tb, xn, pooled);
  k_pool  <<<1, 256, 0, stream>>>(pooled, pw, pb, ntok);
  k_cs    <<<2048, 256, 0, stream>>>(xn, w1, w2, scores);
  k_stats <<<512, 256, 0, stream>>>(scores, part);
  k_sfinal<<<1, 64, 0, stream>>>(part, Mv, Li);
  k_sel   <<<512, 256, 0, stream>>>(scores, Mv, Li, ntok, sel);
  k_og    <<<dim3(128, 4), 256, 0, stream>>>(xn, wf, sel, ntok, oacc);
  k_ofinal<<<1, 256, 0, stream>>>(oacc, ng, nb, ntok, outp);
}

// Round 2
// 611.414 us; speedup vs baseline: 4.2719x; 4.2719x over previous
//
#include <hip/hip_runtime.h>
#include <hip/hip_bf16.h>

#define DEV __device__ __forceinline__

constexpr int N = 65536;
constexpr int C = 768;
constexpr int T = 64;

using bf16 = __hip_bfloat16;
using short8 = __attribute__((ext_vector_type(8))) short;
using f32x4  = __attribute__((ext_vector_type(4))) float;

DEV ushort f2bits(float v) { union { __hip_bfloat16 h; ushort u; } x; x.h = __float2bfloat16(v); return x.u; }
DEV float bits2f(ushort b) { union { uint u; float f; } x; x.u = ((uint)b) << 16; return x.f; }
DEV f32x4 mfma16(short8 a, short8 b, f32x4 c) { return __builtin_amdgcn_mfma_f32_16x16x32_bf16(a, b, c, 0, 0, 0); }
// XOR swizzle: 16B-unit permutation within a 128B (64-short) row. Bijective per row.
DEV int swz(int row, int col) { return row * 64 + (col ^ ((row & 7) << 3)); }

DEV float wredsum(float v) {
#pragma unroll
  for (int o = 32; o > 0; o >>= 1) v += __shfl_xor(v, o, 64);
  return v;
}

// ---------------------------------------------------------------------------
// K1: LayerNorm rows of x -> xn (bf16), accumulate pooled sums. float4 loads,
// packed bf16x4 (uint2) stores.
// ---------------------------------------------------------------------------
__global__ __launch_bounds__(256, 4) void k_ln(const float4* __restrict__ x,
                                               const float4* __restrict__ gam,
                                               const float4* __restrict__ bet,
                                               uint2* __restrict__ xn,
                                               float* __restrict__ pooled) {
  const int tid = threadIdx.x, wave = tid >> 6, lane = tid & 63;
  float4 gg[3], bb[3], pool[3];
#pragma unroll
  for (int j = 0; j < 3; j++) {
    gg[j] = gam[lane + 64 * j]; bb[j] = bet[lane + 64 * j];
    pool[j] = make_float4(0.f, 0.f, 0.f, 0.f);
  }
  const int r0 = (blockIdx.x * 4 + wave) * 16;
  for (int r = r0; r < r0 + 16; ++r) {
    const float4* xr = x + (size_t)r * 192;
    float4 v[3]; float s = 0.f;
#pragma unroll
    for (int j = 0; j < 3; j++) { v[j] = xr[lane + 64 * j]; s += v[j].x + v[j].y + v[j].z + v[j].w; }
    s = wredsum(s);
    const float mu = s * (1.f / C);
    float q = 0.f;
#pragma unroll
    for (int j = 0; j < 3; j++) {
      float a = v[j].x - mu, b = v[j].y - mu, c = v[j].z - mu, d = v[j].w - mu;
      q += a * a + b * b + c * c + d * d;
    }
    q = wredsum(q);
    const float rs = rsqrtf(q * (1.f / C) + 1e-5f);
    uint2* xo = xn + (size_t)r * 192;
#pragma unroll
    for (int j = 0; j < 3; j++) {
      float y0 = (v[j].x - mu) * rs * gg[j].x + bb[j].x;
      float y1 = (v[j].y - mu) * rs * gg[j].y + bb[j].y;
      float y2 = (v[j].z - mu) * rs * gg[j].z + bb[j].z;
      float y3 = (v[j].w - mu) * rs * gg[j].w + bb[j].w;
      pool[j].x += y0; pool[j].y += y1; pool[j].z += y2; pool[j].w += y3;
      xo[lane + 64 * j] = make_uint2((uint)f2bits(y0) | ((uint)f2bits(y1) << 16),
                                     (uint)f2bits(y2) | ((uint)f2bits(y3) << 16));
    }
  }
  __shared__ float lp[4][C];
#pragma unroll
  for (int j = 0; j < 3; j++) {
    int base = (lane + 64 * j) * 4;
    lp[wave][base] = pool[j].x; lp[wave][base + 1] = pool[j].y;
    lp[wave][base + 2] = pool[j].z; lp[wave][base + 3] = pool[j].w;
  }
  __syncthreads();
  for (int c = tid; c < C; c += 256)
    atomicAdd(&pooled[c], lp[0][c] + lp[1][c] + lp[2][c] + lp[3][c]);
}

// ---------------------------------------------------------------------------
// K2: pooled -> ratio -> num_tokens
// ---------------------------------------------------------------------------
__global__ __launch_bounds__(256) void k_pool(const float* __restrict__ pooled,
                                              const float* __restrict__ pw,
                                              const float* __restrict__ pb,
                                              int* __restrict__ ntok) {
  const int tid = threadIdx.x, wave = tid >> 6, lane = tid & 63;
  float a = 0.f;
  for (int c = tid; c < C; c += 256) a += pooled[c] * (1.f / N) * pw[c];
  a = wredsum(a);
  __shared__ float red[4];
  if (lane == 0) red[wave] = a;
  __syncthreads();
  if (tid == 0) {
    float d = red[0] + red[1] + red[2] + red[3] + pb[0];
    float ratio = 1.f / (1.f + expf(-d));
    int nt = (int)floorf(ratio * 64.f);
    nt = nt < 0 ? 0 : (nt > 64 ? 64 : nt);
    *ntok = nt;
  }
}

// ---------------------------------------------------------------------------
// K3 (MFMA): fused grouped conv1 + ReLU + scores GEMM.
// Block = 4 waves x 16 rows = 64 rows. Per group g:
//   stage1: hT[o,n] = relu(w1[g] @ xn_gT)   (A=w1 LDS bf16 K-pad zeros, B=xn global)
//   stage2: scoresT[t,n] += w2_g @ hT       (A=w2 LDS bf16 K-pad zeros, B=h LDS)
// h LDS rows XOR-swizzled; pad region zero-initialized once (bijective swizzle
// keeps the never-written physical slots exactly the images of o>=48).
// ---------------------------------------------------------------------------
__global__ __launch_bounds__(256, 4) void k_cs(const short* __restrict__ xn,
                                               const float* __restrict__ w1,
                                               const float* __restrict__ w2,
                                               float* __restrict__ scores) {
  __shared__ __align__(16) short w1s[48 * 64];
  __shared__ __align__(16) short w2s[64 * 64];
  __shared__ __align__(16) short hs[4][16 * 64];
  const int tid = threadIdx.x, wave = tid >> 6, lane = tid & 63;
  const int l15 = lane & 15, g2 = lane >> 4;
  { uint* hz = (uint*)hs; for (int i = tid; i < 2048; i += 256) hz[i] = 0u; }
  const int row0 = blockIdx.x * 64 + wave * 16;
  f32x4 acc[4];
#pragma unroll
  for (int t = 0; t < 4; ++t) acc[t] = (f32x4){0.f, 0.f, 0.f, 0.f};
  const short* xrow = xn + (size_t)(row0 + l15) * 768;
  short* hw = hs[wave];

  for (int g = 0; g < 16; ++g) {
    __syncthreads();
    for (int i = tid; i < 3072; i += 256) {
      int o = i >> 6, c = i & 63;
      w1s[swz(o, c)] = (c < 48) ? (short)f2bits(w1[g * 2304 + o * 48 + c]) : (short)0;
    }
    for (int i = tid; i < 4096; i += 256) {
      int t = i >> 6, c = i & 63;
      w2s[swz(t, c)] = (c < 48) ? (short)f2bits(w2[t * 768 + g * 48 + c]) : (short)0;
    }
    __syncthreads();
    // stage1: B-frags from global xn (k-tile1 over-read is multiplied by A-side zeros)
    short8 bx0 = *(const short8*)(xrow + g * 48 + g2 * 8);
    short8 bx1 = *(const short8*)(xrow + g * 48 + 32 + g2 * 8);
#pragma unroll
    for (int ot = 0; ot < 3; ++ot) {
      int ar = ot * 16 + l15;
      short8 a0 = *(const short8*)&w1s[swz(ar, g2 * 8)];
      short8 a1 = *(const short8*)&w1s[swz(ar, 32 + g2 * 8)];
      f32x4 h = (f32x4){0.f, 0.f, 0.f, 0.f};
      h = mfma16(a0, bx0, h);
      h = mfma16(a1, bx1, h);
      // D: col n = l15, rows o = ot*16 + g2*4 + r  -> hw[n][o..o+4) after relu
      uint lo = (uint)f2bits(fmaxf(h[0], 0.f)) | ((uint)f2bits(fmaxf(h[1], 0.f)) << 16);
      uint hi = (uint)f2bits(fmaxf(h[2], 0.f)) | ((uint)f2bits(fmaxf(h[3], 0.f)) << 16);
      *(uint2*)&hw[swz(l15, ot * 16 + g2 * 4)] = make_uint2(lo, hi);
    }
    // stage2 (same-wave LDS dependency; compiler inserts lgkmcnt)
    short8 hb0 = *(const short8*)&hw[swz(l15, g2 * 8)];
    short8 hb1 = *(const short8*)&hw[swz(l15, 32 + g2 * 8)];
#pragma unroll
    for (int tt = 0; tt < 4; ++tt) {
      int r = tt * 16 + l15;
      short8 a0 = *(const short8*)&w2s[swz(r, g2 * 8)];
      short8 a1 = *(const short8*)&w2s[swz(r, 32 + g2 * 8)];
      acc[tt] = mfma16(a0, hb0, acc[tt]);
      acc[tt] = mfma16(a1, hb1, acc[tt]);
    }
  }
#pragma unroll
  for (int tt = 0; tt < 4; ++tt)
#pragma unroll
    for (int r = 0; r < 4; ++r)
      scores[(size_t)(tt * 16 + g2 * 4 + r) * N + row0 + l15] = acc[tt][r];
}

// ---------------------------------------------------------------------------
// K4: per-(t, segment) online softmax partial stats
// ---------------------------------------------------------------------------
__global__ __launch_bounds__(256) void k_stats(const float* __restrict__ scores,
                                               float2* __restrict__ part) {
  const int t = blockIdx.x >> 3, s = blockIdx.x & 7;
  const float* row = scores + (size_t)t * N + s * 8192;
  float m = -1e30f, l = 0.f;
  for (int i = threadIdx.x; i < 8192; i += 256) {
    float v = row[i];
    if (v > m) { l = l * __expf(m - v) + 1.f; m = v; }
    else       { l += __expf(v - m); }
  }
#pragma unroll
  for (int o = 32; o > 0; o >>= 1) {
    float m2 = __shfl_xor(m, o, 64), l2 = __shfl_xor(l, o, 64);
    float M = fmaxf(m, m2);
    l = l * __expf(m - M) + l2 * __expf(m2 - M); m = M;
  }
  __shared__ float sm[4], sl[4];
  const int wave = threadIdx.x >> 6, lane = threadIdx.x & 63;
  if (lane == 0) { sm[wave] = m; sl[wave] = l; }
  __syncthreads();
  if (threadIdx.x == 0) {
    float M = sm[0], L = sl[0];
    for (int w = 1; w < 4; w++) { float M2 = fmaxf(M, sm[w]); L = L * __expf(M - M2) + sl[w] * __expf(sm[w] - M2); M = M2; }
    part[blockIdx.x] = make_float2(M, L);
  }
}

__global__ void k_sfinal(const float2* __restrict__ part, float* __restrict__ Mv,
                         float* __restrict__ Li) {
  int t = threadIdx.x;  // 64 threads
  float M = -1e30f, L = 0.f;
  for (int s = 0; s < 8; s++) {
    float2 p = part[t * 8 + s];
    float M2 = fmaxf(M, p.x);
    L = L * __expf(M - M2) + p.y * __expf(p.x - M2); M = M2;
  }
  Mv[t] = M; Li[t] = 1.f / L;
}

__global__ __launch_bounds__(256) void k_sel(const float* __restrict__ scores,
                                             const float* __restrict__ Mv,
                                             const float* __restrict__ Li,
                                             const int* __restrict__ ntokp,
                                             float* __restrict__ sel) {
  const int t = blockIdx.x >> 3, s = blockIdx.x & 7;
  const size_t base = (size_t)t * N + s * 8192;
  const bool on = t < *ntokp;
  const float m = Mv[t], li = Li[t];
  for (int i = threadIdx.x; i < 8192; i += 256)
    sel[base + i] = on ? __expf(scores[base + i] - m) * li : 0.f;
}

// ---------------------------------------------------------------------------
// K7 (MFMA): out_part[nb][t][cb-block] = sum over 512 rows of sel[t,n]*feat[n,c]
// 8 waves: conv assignment (group = w>>1, n-half = w&1) fills featT[192][32] in
// LDS (swizzled); og assignment (tt = w>>1, c-half = w&1) does A=sel x B=featT.
// bf16 partials, no atomics.
// ---------------------------------------------------------------------------
__global__ __launch_bounds__(512, 4) void k_og(const short* __restrict__ xn,
                                               const float* __restrict__ wf,
                                               const float* __restrict__ sel,
                                               const int* __restrict__ ntokp,
                                               ushort* __restrict__ out_part) {
  __shared__ __align__(16) short wfs[4][48 * 64];  // 24 KB
  __shared__ __align__(16) short ft[192 * 64];     // 24 KB (featT, swizzled rows)
  const int tid = threadIdx.x, wave = tid >> 6, lane = tid & 63;
  const int l15 = lane & 15, g2 = lane >> 4;
  const int cb = blockIdx.y, nb = blockIdx.x;
  for (int i = tid; i < 4 * 3072; i += 512) {
    int g = i / 3072, rr = (i - g * 3072) >> 6, c = i & 63;
    wfs[g][swz(rr, c)] = (c < 48) ? (short)f2bits(wf[(size_t)(cb * 4 + g) * 2304 + rr * 48 + c]) : (short)0;
  }
  const int ntok = *ntokp;
  const int tt = wave >> 1, chalf = wave & 1;
  const int gq = wave >> 1, ntq = wave & 1;
  const bool act = (tt * 16) < ntok;
  f32x4 acc[6];
#pragma unroll
  for (int k = 0; k < 6; ++k) acc[k] = (f32x4){0.f, 0.f, 0.f, 0.f};

  for (int ns = 0; ns < 16; ++ns) {
    const int n0 = nb * 512 + ns * 32;
    __syncthreads();  // featT readers of previous iter done
    {
      const short* xr = xn + (size_t)(n0 + ntq * 16 + l15) * 768 + (cb * 4 + gq) * 48;
      short8 b0 = *(const short8*)(xr + g2 * 8);
      short8 b1 = *(const short8*)(xr + 32 + g2 * 8);
#pragma unroll
      for (int ot = 0; ot < 3; ++ot) {
        int ar = ot * 16 + l15;
        short8 a0 = *(const short8*)&wfs[gq][swz(ar, g2 * 8)];
        short8 a1 = *(const short8*)&wfs[gq][swz(ar, 32 + g2 * 8)];
        f32x4 d = (f32x4){0.f, 0.f, 0.f, 0.f};
        d = mfma16(a0, b0, d);
        d = mfma16(a1, b1, d);
        int n = ntq * 16 + l15;
#pragma unroll
        for (int r = 0; r < 4; ++r) {
          int c = gq * 48 + ot * 16 + g2 * 4 + r;
          ft[c * 64 + (n ^ ((c & 7) << 3))] = (short)f2bits(d[r]);
        }
      }
    }
    __syncthreads();  // featT ready
    if (act) {
      const float* sr = sel + (size_t)(tt * 16 + l15) * N + n0 + g2 * 8;
      float4 s0 = *(const float4*)sr;
      float4 s1 = *(const float4*)(sr + 4);
      short8 pa;
      pa[0] = (short)f2bits(s0.x); pa[1] = (short)f2bits(s0.y);
      pa[2] = (short)f2bits(s0.z); pa[3] = (short)f2bits(s0.w);
      pa[4] = (short)f2bits(s1.x); pa[5] = (short)f2bits(s1.y);
      pa[6] = (short)f2bits(s1.z); pa[7] = (short)f2bits(s1.w);
#pragma unroll
      for (int ct = 0; ct < 6; ++ct) {
        int c = (chalf * 6 + ct) * 16 + l15;
        short8 fb = *(const short8*)&ft[c * 64 + ((g2 * 8) ^ ((c & 7) << 3))];
        acc[ct] = mfma16(pa, fb, acc[ct]);
      }
    }
  }
#pragma unroll
  for (int ct = 0; ct < 6; ++ct)
#pragma unroll
    for (int r = 0; r < 4; ++r) {
      int t = tt * 16 + g2 * 4 + r;
      int c = cb * 192 + (chalf * 6 + ct) * 16 + l15;
      out_part[(size_t)nb * (64 * 768) + t * 768 + c] = f2bits(acc[ct][r]);
    }
}

// K7b: reduce bf16 partials over 128 n-blocks -> fp32 oacc
__global__ __launch_bounds__(256) void k_red(const ushort* __restrict__ out_part,
                                             float* __restrict__ oacc) {
  int i = blockIdx.x * 256 + threadIdx.x;  // 0..49151
  float s = 0.f;
  for (int nb = 0; nb < 128; ++nb) s += bits2f(out_part[(size_t)nb * (64 * 768) + i]);
  oacc[i] = s;
}

// K8: final LayerNorm of out rows + mask
__global__ __launch_bounds__(256) void k_ofinal(const float* __restrict__ out_acc,
                                                const float* __restrict__ ng,
                                                const float* __restrict__ nb_,
                                                const int* __restrict__ ntokp,
                                                float* __restrict__ outp) {
  const int tid = threadIdx.x, wave = tid >> 6, lane = tid & 63;
  const int ntok = *ntokp;
  for (int t = wave; t < T; t += 4) {
    const float* r = out_acc + t * C;
    float v[12]; float s = 0.f;
#pragma unroll
    for (int j = 0; j < 12; j++) { v[j] = r[lane + 64 * j]; s += v[j]; }
    s = wredsum(s); float mu = s * (1.f / C);
    float q = 0.f;
#pragma unroll
    for (int j = 0; j < 12; j++) { float d = v[j] - mu; q += d * d; }
    q = wredsum(q); float rs = rsqrtf(q * (1.f / C) + 1e-5f);
    float* o = outp + t * C;
#pragma unroll
    for (int j = 0; j < 12; j++) {
      int c = lane + 64 * j;
      float y = (v[j] - mu) * rs * ng[c] + nb_[c];
      o[c] = (t < ntok) ? y : 0.f;
    }
  }
}

// ---------------------------------------------------------------------------
extern "C" void kernel_launch(void* const* d_in, const int* in_sizes, int n_in,
                              void* d_out, int out_size, void* d_ws, size_t ws_size,
                              hipStream_t stream) {
  const float* x  = (const float*)d_in[0];
  const float* tg = (const float*)d_in[1];
  const float* tb = (const float*)d_in[2];
  const float* w1 = (const float*)d_in[3];
  const float* w2 = (const float*)d_in[4];
  const float* wf = (const float*)d_in[5];
  const float* pw = (const float*)d_in[6];
  const float* pb = (const float*)d_in[7];
  const float* ng = (const float*)d_in[8];
  const float* nb = (const float*)d_in[9];

  char* ws = (char*)d_ws;
  // small block
  float*  pooled = (float*)(ws + 0);          // 3,072 B
  float2* part   = (float2*)(ws + 4096);      // 4,096 B
  float*  Mv     = (float*)(ws + 8192);
  float*  Li     = (float*)(ws + 8448);
  int*    ntok   = (int*)(ws + 8704);
  // big buffers
  short*  xn     = (short*)(ws + 16384);           // 100,663,296 B, ends 100,679,680
  float*  scores = (float*)(ws + 100679680);       // 16,777,216 B, ends 117,456,896
  // after k_sel, scores region is dead -> overlay:
  ushort* opart  = (ushort*)(ws + 100679680);      // 12,582,912 B
  float*  oacc   = (float*)(ws + 100679680 + 12582912);  // 196,608 B

  float* sel  = (float*)d_out;
  float* outp = (float*)d_out + (size_t)T * N;

  hipMemsetAsync(pooled, 0, C * sizeof(float), stream);

  k_ln    <<<1024, 256, 0, stream>>>((const float4*)x, (const float4*)tg, (const float4*)tb,
                                     (uint2*)xn, pooled);
  k_pool  <<<1, 256, 0, stream>>>(pooled, pw, pb, ntok);
  k_cs    <<<1024, 256, 0, stream>>>(xn, w1, w2, scores);
  k_stats <<<512, 256, 0, stream>>>(scores, part);
  k_sfinal<<<1, 64, 0, stream>>>(part, Mv, Li);
  k_sel   <<<512, 256, 0, stream>>>(scores, Mv, Li, ntok, sel);
  k_og    <<<dim3(128, 4), 512, 0, stream>>>(xn, wf, sel, ntok, opart);
  k_red   <<<192, 256, 0, stream>>>(opart, oacc);
  k_ofinal<<<1, 256, 0, stream>>>(oacc, ng, nb, ntok, outp);
}

// Round 3
// 465.402 us; speedup vs baseline: 5.6121x; 1.3137x over previous
//
#include <hip/hip_runtime.h>
#include <hip/hip_bf16.h>

#define DEV __device__ __forceinline__

constexpr int N = 65536;
constexpr int C = 768;
constexpr int T = 64;

using bf16 = __hip_bfloat16;
using short8 = __attribute__((ext_vector_type(8))) short;
using f32x4  = __attribute__((ext_vector_type(4))) float;

DEV ushort f2bits(float v) { union { __hip_bfloat16 h; ushort u; } x; x.h = __float2bfloat16(v); return x.u; }
DEV float bits2f(ushort b) { union { uint u; float f; } x; x.u = ((uint)b) << 16; return x.f; }
DEV f32x4 mfma16(short8 a, short8 b, f32x4 c) { return __builtin_amdgcn_mfma_f32_16x16x32_bf16(a, b, c, 0, 0, 0); }
// XOR swizzle: 16B-unit permutation within a 128B (64-short) row. Bijective per row.
DEV int swz(int row, int col) { return row * 64 + (col ^ ((row & 7) << 3)); }

DEV float wredsum(float v) {
#pragma unroll
  for (int o = 32; o > 0; o >>= 1) v += __shfl_xor(v, o, 64);
  return v;
}

// ---------------------------------------------------------------------------
// K0: pack w1/w2/wf into MFMA-fragment-ordered bf16 arrays, zero-padded K 48->64.
// Layout: frag f = (g*NT + t_or_o_tile)*2 + ktile; element = [f*512 + lane*8 + j]
//   value = W[row = tile*16 + (lane&15)][k = ktile*32 + ((lane>>4)&3)*8 + j]
// ---------------------------------------------------------------------------
__global__ __launch_bounds__(256) void k_wprep(const float* __restrict__ w1,
                                               const float* __restrict__ w2,
                                               const float* __restrict__ wf,
                                               short* __restrict__ w1p,
                                               short* __restrict__ w2p,
                                               short* __restrict__ wfp) {
  const int b = blockIdx.x, tid = threadIdx.x;
  if (b < 192) {            // w1p: 16 g * 3 ot * 2 kt * 512 = 49152
    int idx = b * 256 + tid;
    int j = idx & 7, lane = (idx >> 3) & 63, u = idx >> 9;
    int kt = u & 1, v = u >> 1, ot = v % 3, g = v / 3;
    int o = ot * 16 + (lane & 15), k = kt * 32 + ((lane >> 4) & 3) * 8 + j;
    w1p[idx] = (k < 48) ? (short)f2bits(w1[g * 2304 + o * 48 + k]) : (short)0;
  } else if (b < 448) {     // w2p: 16 g * 4 tt * 2 kt * 512 = 65536
    int idx = (b - 192) * 256 + tid;
    int j = idx & 7, lane = (idx >> 3) & 63, u = idx >> 9;
    int kt = u & 1, v = u >> 1, tt = v & 3, g = v >> 2;
    int t = tt * 16 + (lane & 15), k = kt * 32 + ((lane >> 4) & 3) * 8 + j;
    w2p[idx] = (k < 48) ? (short)f2bits(w2[t * 768 + g * 48 + k]) : (short)0;
  } else {                  // wfp: like w1p
    int idx = (b - 448) * 256 + tid;
    int j = idx & 7, lane = (idx >> 3) & 63, u = idx >> 9;
    int kt = u & 1, v = u >> 1, ot = v % 3, g = v / 3;
    int o = ot * 16 + (lane & 15), k = kt * 32 + ((lane >> 4) & 3) * 8 + j;
    wfp[idx] = (k < 48) ? (short)f2bits(wf[g * 2304 + o * 48 + k]) : (short)0;
  }
}

// ---------------------------------------------------------------------------
// K1: LayerNorm rows of x -> xn (bf16) + pooled sums. Single-pass moments.
// ---------------------------------------------------------------------------
__global__ __launch_bounds__(256, 4) void k_ln(const float4* __restrict__ x,
                                               const float4* __restrict__ gam,
                                               const float4* __restrict__ bet,
                                               uint2* __restrict__ xn,
                                               float* __restrict__ pooled) {
  const int tid = threadIdx.x, wave = tid >> 6, lane = tid & 63;
  float4 gg[3], bb[3], pool[3];
#pragma unroll
  for (int j = 0; j < 3; j++) {
    gg[j] = gam[lane + 64 * j]; bb[j] = bet[lane + 64 * j];
    pool[j] = make_float4(0.f, 0.f, 0.f, 0.f);
  }
  const int r0 = (blockIdx.x * 4 + wave) * 16;
  for (int r = r0; r < r0 + 16; ++r) {
    const float4* xr = x + (size_t)r * 192;
    float4 v[3]; float s = 0.f, q = 0.f;
#pragma unroll
    for (int j = 0; j < 3; j++) {
      v[j] = xr[lane + 64 * j];
      s += v[j].x + v[j].y + v[j].z + v[j].w;
      q += v[j].x * v[j].x + v[j].y * v[j].y + v[j].z * v[j].z + v[j].w * v[j].w;
    }
    s = wredsum(s); q = wredsum(q);
    const float mu = s * (1.f / C);
    const float rs = rsqrtf(q * (1.f / C) - mu * mu + 1e-5f);
    uint2* xo = xn + (size_t)r * 192;
#pragma unroll
    for (int j = 0; j < 3; j++) {
      float y0 = (v[j].x - mu) * rs * gg[j].x + bb[j].x;
      float y1 = (v[j].y - mu) * rs * gg[j].y + bb[j].y;
      float y2 = (v[j].z - mu) * rs * gg[j].z + bb[j].z;
      float y3 = (v[j].w - mu) * rs * gg[j].w + bb[j].w;
      pool[j].x += y0; pool[j].y += y1; pool[j].z += y2; pool[j].w += y3;
      xo[lane + 64 * j] = make_uint2((uint)f2bits(y0) | ((uint)f2bits(y1) << 16),
                                     (uint)f2bits(y2) | ((uint)f2bits(y3) << 16));
    }
  }
  __shared__ float lp[4][C];
#pragma unroll
  for (int j = 0; j < 3; j++) {
    int base = (lane + 64 * j) * 4;
    lp[wave][base] = pool[j].x; lp[wave][base + 1] = pool[j].y;
    lp[wave][base + 2] = pool[j].z; lp[wave][base + 3] = pool[j].w;
  }
  __syncthreads();
  for (int c = tid; c < C; c += 256)
    atomicAdd(&pooled[c], lp[0][c] + lp[1][c] + lp[2][c] + lp[3][c]);
}

// ---------------------------------------------------------------------------
// K2: pooled -> ratio -> num_tokens
// ---------------------------------------------------------------------------
__global__ __launch_bounds__(256) void k_pool(const float* __restrict__ pooled,
                                              const float* __restrict__ pw,
                                              const float* __restrict__ pb,
                                              int* __restrict__ ntok) {
  const int tid = threadIdx.x, wave = tid >> 6, lane = tid & 63;
  float a = 0.f;
  for (int c = tid; c < C; c += 256) a += pooled[c] * (1.f / N) * pw[c];
  a = wredsum(a);
  __shared__ float red[4];
  if (lane == 0) red[wave] = a;
  __syncthreads();
  if (tid == 0) {
    float d = red[0] + red[1] + red[2] + red[3] + pb[0];
    float ratio = 1.f / (1.f + expf(-d));
    int nt = (int)floorf(ratio * 64.f);
    nt = nt < 0 ? 0 : (nt > 64 ? 64 : nt);
    *ntok = nt;
  }
}

// ---------------------------------------------------------------------------
// K3 (MFMA, barrier-free): fused grouped conv1 + ReLU + scores GEMM.
// 4 waves x 16 rows. Weights come as fragment-ordered bf16 (global, L1/L2-hot).
// Only LDS use: per-wave h transpose (swizzled), within-wave dependency only.
// ---------------------------------------------------------------------------
__global__ __launch_bounds__(256, 4) void k_cs(const short* __restrict__ xn,
                                               const short* __restrict__ w1p,
                                               const short* __restrict__ w2p,
                                               float* __restrict__ scores) {
  __shared__ __align__(16) short hs[4][16 * 64];
  const int tid = threadIdx.x, wave = tid >> 6, lane = tid & 63;
  const int l15 = lane & 15, g2 = lane >> 4;
  short* hw = hs[wave];
  {  // zero per-wave pad region (cols 48..63 read as k-slots vs zero A -> must not be NaN)
    uint* hz = (uint*)hw;
    for (int i = lane; i < 512; i += 64) hz[i] = 0u;
  }
  const int row0 = blockIdx.x * 64 + wave * 16;
  f32x4 acc[4];
#pragma unroll
  for (int t = 0; t < 4; ++t) acc[t] = (f32x4){0.f, 0.f, 0.f, 0.f};
  const short* xrow = xn + (size_t)(row0 + l15) * 768;
  const int lo8 = lane * 8;

  short8 bx0 = *(const short8*)(xrow + g2 * 8);
  short8 bx1 = *(const short8*)(xrow + 32 + g2 * 8);
  for (int g = 0; g < 16; ++g) {
    // prefetch next group's xn B-frags (k-tile1 over-read multiplied by A-side zeros)
    const int gn = (g < 15) ? g + 1 : 15;
    short8 nbx0 = *(const short8*)(xrow + gn * 48 + g2 * 8);
    short8 nbx1 = *(const short8*)(xrow + gn * 48 + 32 + g2 * 8);
    const short* w1g = w1p + g * 3072;
#pragma unroll
    for (int ot = 0; ot < 3; ++ot) {
      short8 a0 = *(const short8*)(w1g + (ot * 2 + 0) * 512 + lo8);
      short8 a1 = *(const short8*)(w1g + (ot * 2 + 1) * 512 + lo8);
      f32x4 h = (f32x4){0.f, 0.f, 0.f, 0.f};
      h = mfma16(a0, bx0, h);
      h = mfma16(a1, bx1, h);
      uint lo = (uint)f2bits(fmaxf(h[0], 0.f)) | ((uint)f2bits(fmaxf(h[1], 0.f)) << 16);
      uint hi = (uint)f2bits(fmaxf(h[2], 0.f)) | ((uint)f2bits(fmaxf(h[3], 0.f)) << 16);
      *(uint2*)&hw[swz(l15, ot * 16 + g2 * 4)] = make_uint2(lo, hi);
    }
    short8 hb0 = *(const short8*)&hw[swz(l15, g2 * 8)];
    short8 hb1 = *(const short8*)&hw[swz(l15, 32 + g2 * 8)];
    const short* w2g = w2p + g * 4096;
#pragma unroll
    for (int tt = 0; tt < 4; ++tt) {
      short8 a0 = *(const short8*)(w2g + (tt * 2 + 0) * 512 + lo8);
      short8 a1 = *(const short8*)(w2g + (tt * 2 + 1) * 512 + lo8);
      acc[tt] = mfma16(a0, hb0, acc[tt]);
      acc[tt] = mfma16(a1, hb1, acc[tt]);
    }
    bx0 = nbx0; bx1 = nbx1;
  }
#pragma unroll
  for (int tt = 0; tt < 4; ++tt)
#pragma unroll
    for (int r = 0; r < 4; ++r)
      scores[(size_t)(tt * 16 + g2 * 4 + r) * N + row0 + l15] = acc[tt][r];
}

// ---------------------------------------------------------------------------
// K4: per-(t, segment) online softmax partial stats
// ---------------------------------------------------------------------------
__global__ __launch_bounds__(256) void k_stats(const float* __restrict__ scores,
                                               float2* __restrict__ part) {
  const int t = blockIdx.x >> 3, s = blockIdx.x & 7;
  const float* row = scores + (size_t)t * N + s * 8192;
  float m = -1e30f, l = 0.f;
  for (int i = threadIdx.x; i < 8192; i += 256) {
    float v = row[i];
    if (v > m) { l = l * __expf(m - v) + 1.f; m = v; }
    else       { l += __expf(v - m); }
  }
#pragma unroll
  for (int o = 32; o > 0; o >>= 1) {
    float m2 = __shfl_xor(m, o, 64), l2 = __shfl_xor(l, o, 64);
    float M = fmaxf(m, m2);
    l = l * __expf(m - M) + l2 * __expf(m2 - M); m = M;
  }
  __shared__ float sm[4], sl[4];
  const int wave = threadIdx.x >> 6, lane = threadIdx.x & 63;
  if (lane == 0) { sm[wave] = m; sl[wave] = l; }
  __syncthreads();
  if (threadIdx.x == 0) {
    float M = sm[0], L = sl[0];
    for (int w = 1; w < 4; w++) { float M2 = fmaxf(M, sm[w]); L = L * __expf(M - M2) + sl[w] * __expf(sm[w] - M2); M = M2; }
    part[blockIdx.x] = make_float2(M, L);
  }
}

__global__ void k_sfinal(const float2* __restrict__ part, float* __restrict__ Mv,
                         float* __restrict__ Li) {
  int t = threadIdx.x;  // 64 threads
  float M = -1e30f, L = 0.f;
  for (int s = 0; s < 8; s++) {
    float2 p = part[t * 8 + s];
    float M2 = fmaxf(M, p.x);
    L = L * __expf(M - M2) + p.y * __expf(p.x - M2); M = M2;
  }
  Mv[t] = M; Li[t] = 1.f / L;
}

__global__ __launch_bounds__(256) void k_sel(const float* __restrict__ scores,
                                             const float* __restrict__ Mv,
                                             const float* __restrict__ Li,
                                             const int* __restrict__ ntokp,
                                             float* __restrict__ sel) {
  const int t = blockIdx.x >> 3, s = blockIdx.x & 7;
  const size_t base = (size_t)t * N + s * 8192;
  const bool on = t < *ntokp;
  const float m = Mv[t], li = Li[t];
  for (int i = threadIdx.x; i < 8192; i += 256)
    sel[base + i] = on ? __expf(scores[base + i] - m) * li : 0.f;
}

// ---------------------------------------------------------------------------
// K7 (MFMA): out_part[nb][t][c-block]. Conv waves fill featT in LDS (swizzled);
// og waves MFMA A=sel x B=featT. wf frags hoisted to registers (ns-invariant).
// ---------------------------------------------------------------------------
__global__ __launch_bounds__(512, 4) void k_og(const short* __restrict__ xn,
                                               const short* __restrict__ wfp,
                                               const float* __restrict__ sel,
                                               const int* __restrict__ ntokp,
                                               ushort* __restrict__ out_part) {
  __shared__ __align__(16) short ft[192 * 64];  // 24 KB (featT, swizzled rows)
  const int tid = threadIdx.x, wave = tid >> 6, lane = tid & 63;
  const int l15 = lane & 15, g2 = lane >> 4;
  const int cb = blockIdx.y, nb = blockIdx.x;
  const int ntok = *ntokp;
  const int tt = wave >> 1, chalf = wave & 1;
  const int gq = wave >> 1, ntq = wave & 1;
  const bool act = (tt * 16) < ntok;
  // hoist wf fragments for this wave's group: constant across all 16 ns iters
  short8 wa0[3], wa1[3];
  {
    const short* wb = wfp + (size_t)(cb * 4 + gq) * 3072 + lane * 8;
#pragma unroll
    for (int ot = 0; ot < 3; ++ot) {
      wa0[ot] = *(const short8*)(wb + (ot * 2 + 0) * 512);
      wa1[ot] = *(const short8*)(wb + (ot * 2 + 1) * 512);
    }
  }
  f32x4 acc[6];
#pragma unroll
  for (int k = 0; k < 6; ++k) acc[k] = (f32x4){0.f, 0.f, 0.f, 0.f};

  for (int ns = 0; ns < 16; ++ns) {
    const int n0 = nb * 512 + ns * 32;
    __syncthreads();  // featT readers of previous iter done
    {
      const short* xr = xn + (size_t)(n0 + ntq * 16 + l15) * 768 + (cb * 4 + gq) * 48;
      short8 b0 = *(const short8*)(xr + g2 * 8);
      short8 b1 = *(const short8*)(xr + 32 + g2 * 8);
#pragma unroll
      for (int ot = 0; ot < 3; ++ot) {
        f32x4 d = (f32x4){0.f, 0.f, 0.f, 0.f};
        d = mfma16(wa0[ot], b0, d);
        d = mfma16(wa1[ot], b1, d);
        int n = ntq * 16 + l15;
#pragma unroll
        for (int r = 0; r < 4; ++r) {
          int c = gq * 48 + ot * 16 + g2 * 4 + r;
          ft[c * 64 + (n ^ ((c & 7) << 3))] = (short)f2bits(d[r]);
        }
      }
    }
    __syncthreads();  // featT ready
    if (act) {
      const float* sr = sel + (size_t)(tt * 16 + l15) * N + n0 + g2 * 8;
      float4 s0 = *(const float4*)sr;
      float4 s1 = *(const float4*)(sr + 4);
      short8 pa;
      pa[0] = (short)f2bits(s0.x); pa[1] = (short)f2bits(s0.y);
      pa[2] = (short)f2bits(s0.z); pa[3] = (short)f2bits(s0.w);
      pa[4] = (short)f2bits(s1.x); pa[5] = (short)f2bits(s1.y);
      pa[6] = (short)f2bits(s1.z); pa[7] = (short)f2bits(s1.w);
#pragma unroll
      for (int ct = 0; ct < 6; ++ct) {
        int c = (chalf * 6 + ct) * 16 + l15;
        short8 fb = *(const short8*)&ft[c * 64 + ((g2 * 8) ^ ((c & 7) << 3))];
        acc[ct] = mfma16(pa, fb, acc[ct]);
      }
    }
  }
#pragma unroll
  for (int ct = 0; ct < 6; ++ct)
#pragma unroll
    for (int r = 0; r < 4; ++r) {
      int t = tt * 16 + g2 * 4 + r;
      int c = cb * 192 + (chalf * 6 + ct) * 16 + l15;
      out_part[(size_t)nb * (64 * 768) + t * 768 + c] = f2bits(acc[ct][r]);
    }
}

// K7b: reduce bf16 partials over 128 n-blocks -> fp32 oacc
__global__ __launch_bounds__(256) void k_red(const ushort* __restrict__ out_part,
                                             float* __restrict__ oacc) {
  int i = blockIdx.x * 256 + threadIdx.x;  // 0..49151
  float s = 0.f;
  for (int nb = 0; nb < 128; ++nb) s += bits2f(out_part[(size_t)nb * (64 * 768) + i]);
  oacc[i] = s;
}

// K8: final LayerNorm of out rows + mask
__global__ __launch_bounds__(256) void k_ofinal(const float* __restrict__ out_acc,
                                                const float* __restrict__ ng,
                                                const float* __restrict__ nb_,
                                                const int* __restrict__ ntokp,
                                                float* __restrict__ outp) {
  const int tid = threadIdx.x, wave = tid >> 6, lane = tid & 63;
  const int ntok = *ntokp;
  for (int t = wave; t < T; t += 4) {
    const float* r = out_acc + t * C;
    float v[12]; float s = 0.f;
#pragma unroll
    for (int j = 0; j < 12; j++) { v[j] = r[lane + 64 * j]; s += v[j]; }
    s = wredsum(s); float mu = s * (1.f / C);
    float q = 0.f;
#pragma unroll
    for (int j = 0; j < 12; j++) { float d = v[j] - mu; q += d * d; }
    q = wredsum(q); float rs = rsqrtf(q * (1.f / C) + 1e-5f);
    float* o = outp + t * C;
#pragma unroll
    for (int j = 0; j < 12; j++) {
      int c = lane + 64 * j;
      float y = (v[j] - mu) * rs * ng[c] + nb_[c];
      o[c] = (t < ntok) ? y : 0.f;
    }
  }
}

// ---------------------------------------------------------------------------
extern "C" void kernel_launch(void* const* d_in, const int* in_sizes, int n_in,
                              void* d_out, int out_size, void* d_ws, size_t ws_size,
                              hipStream_t stream) {
  const float* x  = (const float*)d_in[0];
  const float* tg = (const float*)d_in[1];
  const float* tb = (const float*)d_in[2];
  const float* w1 = (const float*)d_in[3];
  const float* w2 = (const float*)d_in[4];
  const float* wf = (const float*)d_in[5];
  const float* pw = (const float*)d_in[6];
  const float* pb = (const float*)d_in[7];
  const float* ng = (const float*)d_in[8];
  const float* nb = (const float*)d_in[9];

  char* ws = (char*)d_ws;
  // small block
  float*  pooled = (float*)(ws + 0);          // 3,072 B
  float2* part   = (float2*)(ws + 4096);      // 4,096 B
  float*  Mv     = (float*)(ws + 8192);
  float*  Li     = (float*)(ws + 8448);
  int*    ntok   = (int*)(ws + 8704);
  // fragment-ordered weights
  short*  w1p    = (short*)(ws + 16384);      //  98,304 B -> ends 114,688
  short*  w2p    = (short*)(ws + 114688);     // 131,072 B -> ends 245,760
  short*  wfp    = (short*)(ws + 245760);     //  98,304 B -> ends 344,064
  // big buffers
  short*  xn     = (short*)(ws + 344064);     // 100,663,296 B -> ends 101,007,360
  float*  scores = (float*)(ws + 101007360);  // 16,777,216 B -> ends 117,784,576
  // after k_sel, scores region is dead -> overlay:
  ushort* opart  = (ushort*)(ws + 101007360); // 12,582,912 B -> ends 113,590,272
  float*  oacc   = (float*)(ws + 113590272);  // 196,608 B (inside dead scores)

  float* sel  = (float*)d_out;
  float* outp = (float*)d_out + (size_t)T * N;

  hipMemsetAsync(pooled, 0, C * sizeof(float), stream);

  k_wprep <<<640, 256, 0, stream>>>(w1, w2, wf, w1p, w2p, wfp);
  k_ln    <<<1024, 256, 0, stream>>>((const float4*)x, (const float4*)tg, (const float4*)tb,
                                     (uint2*)xn, pooled);
  k_pool  <<<1, 256, 0, stream>>>(pooled, pw, pb, ntok);
  k_cs    <<<1024, 256, 0, stream>>>(xn, w1p, w2p, scores);
  k_stats <<<512, 256, 0, stream>>>(scores, part);
  k_sfinal<<<1, 64, 0, stream>>>(part, Mv, Li);
  k_sel   <<<512, 256, 0, stream>>>(scores, Mv, Li, ntok, sel);
  k_og    <<<dim3(128, 4), 512, 0, stream>>>(xn, wfp, sel, ntok, opart);
  k_red   <<<192, 256, 0, stream>>>(opart, oacc);
  k_ofinal<<<1, 256, 0, stream>>>(oacc, ng, nb, ntok, outp);
}

// Round 6
// 438.437 us; speedup vs baseline: 5.9573x; 1.0615x over previous
//
#include <hip/hip_runtime.h>
#include <hip/hip_bf16.h>

#define DEV __device__ __forceinline__

constexpr int N = 65536;
constexpr int C = 768;
constexpr int T = 64;

using bf16 = __hip_bfloat16;
using short8 = __attribute__((ext_vector_type(8))) short;
using f32x4  = __attribute__((ext_vector_type(4))) float;

DEV ushort f2bits(float v) { union { __hip_bfloat16 h; ushort u; } x; x.h = __float2bfloat16(v); return x.u; }
DEV float bits2f(ushort b) { union { uint u; float f; } x; x.u = ((uint)b) << 16; return x.f; }
DEV f32x4 mfma16(short8 a, short8 b, f32x4 c) { return __builtin_amdgcn_mfma_f32_16x16x32_bf16(a, b, c, 0, 0, 0); }
// XOR swizzle: 16B-unit permutation within a 128B (64-short) row. Bijective per row.
DEV int swz(int row, int col) { return row * 64 + (col ^ ((row & 7) << 3)); }

DEV float wredsum(float v) {
#pragma unroll
  for (int o = 32; o > 0; o >>= 1) v += __shfl_xor(v, o, 64);
  return v;
}

// ---------------------------------------------------------------------------
// K0: pack w1/w2/wf into MFMA-fragment-ordered bf16 arrays, zero-padded K 48->64.
// frag f = (g*NT + tile)*2 + ktile; element [f*512 + lane*8 + j]
//   = W[row = tile*16 + (lane&15)][k = ktile*32 + ((lane>>4)&3)*8 + j]
// ---------------------------------------------------------------------------
__global__ __launch_bounds__(256) void k_wprep(const float* __restrict__ w1,
                                               const float* __restrict__ w2,
                                               const float* __restrict__ wf,
                                               short* __restrict__ w1p,
                                               short* __restrict__ w2p,
                                               short* __restrict__ wfp) {
  const int b = blockIdx.x, tid = threadIdx.x;
  if (b < 192) {            // w1p: 16 g * 3 ot * 2 kt * 512 = 49152
    int idx = b * 256 + tid;
    int j = idx & 7, lane = (idx >> 3) & 63, u = idx >> 9;
    int kt = u & 1, v = u >> 1, ot = v % 3, g = v / 3;
    int o = ot * 16 + (lane & 15), k = kt * 32 + ((lane >> 4) & 3) * 8 + j;
    w1p[idx] = (k < 48) ? (short)f2bits(w1[g * 2304 + o * 48 + k]) : (short)0;
  } else if (b < 448) {     // w2p: 16 g * 4 tt * 2 kt * 512 = 65536
    int idx = (b - 192) * 256 + tid;
    int j = idx & 7, lane = (idx >> 3) & 63, u = idx >> 9;
    int kt = u & 1, v = u >> 1, tt = v & 3, g = v >> 2;
    int t = tt * 16 + (lane & 15), k = kt * 32 + ((lane >> 4) & 3) * 8 + j;
    w2p[idx] = (k < 48) ? (short)f2bits(w2[t * 768 + g * 48 + k]) : (short)0;
  } else {                  // wfp: like w1p
    int idx = (b - 448) * 256 + tid;
    int j = idx & 7, lane = (idx >> 3) & 63, u = idx >> 9;
    int kt = u & 1, v = u >> 1, ot = v % 3, g = v / 3;
    int o = ot * 16 + (lane & 15), k = kt * 32 + ((lane >> 4) & 3) * 8 + j;
    wfp[idx] = (k < 48) ? (short)f2bits(wf[g * 2304 + o * 48 + k]) : (short)0;
  }
}

// ---------------------------------------------------------------------------
// K1: LayerNorm rows of x -> xn (bf16) + pooled sums. Single-pass moments.
// ---------------------------------------------------------------------------
__global__ __launch_bounds__(256, 4) void k_ln(const float4* __restrict__ x,
                                               const float4* __restrict__ gam,
                                               const float4* __restrict__ bet,
                                               uint2* __restrict__ xn,
                                               float* __restrict__ pooled) {
  const int tid = threadIdx.x, wave = tid >> 6, lane = tid & 63;
  float4 gg[3], bb[3], pool[3];
#pragma unroll
  for (int j = 0; j < 3; j++) {
    gg[j] = gam[lane + 64 * j]; bb[j] = bet[lane + 64 * j];
    pool[j] = make_float4(0.f, 0.f, 0.f, 0.f);
  }
  const int r0 = (blockIdx.x * 4 + wave) * 16;
  for (int r = r0; r < r0 + 16; ++r) {
    const float4* xr = x + (size_t)r * 192;
    float4 v[3]; float s = 0.f, q = 0.f;
#pragma unroll
    for (int j = 0; j < 3; j++) {
      v[j] = xr[lane + 64 * j];
      s += v[j].x + v[j].y + v[j].z + v[j].w;
      q += v[j].x * v[j].x + v[j].y * v[j].y + v[j].z * v[j].z + v[j].w * v[j].w;
    }
    s = wredsum(s); q = wredsum(q);
    const float mu = s * (1.f / C);
    const float rs = rsqrtf(q * (1.f / C) - mu * mu + 1e-5f);
    uint2* xo = xn + (size_t)r * 192;
#pragma unroll
    for (int j = 0; j < 3; j++) {
      float y0 = (v[j].x - mu) * rs * gg[j].x + bb[j].x;
      float y1 = (v[j].y - mu) * rs * gg[j].y + bb[j].y;
      float y2 = (v[j].z - mu) * rs * gg[j].z + bb[j].z;
      float y3 = (v[j].w - mu) * rs * gg[j].w + bb[j].w;
      pool[j].x += y0; pool[j].y += y1; pool[j].z += y2; pool[j].w += y3;
      xo[lane + 64 * j] = make_uint2((uint)f2bits(y0) | ((uint)f2bits(y1) << 16),
                                     (uint)f2bits(y2) | ((uint)f2bits(y3) << 16));
    }
  }
  __shared__ float lp[4][C];
#pragma unroll
  for (int j = 0; j < 3; j++) {
    int base = (lane + 64 * j) * 4;
    lp[wave][base] = pool[j].x; lp[wave][base + 1] = pool[j].y;
    lp[wave][base + 2] = pool[j].z; lp[wave][base + 3] = pool[j].w;
  }
  __syncthreads();
  for (int c = tid; c < C; c += 256)
    atomicAdd(&pooled[c], lp[0][c] + lp[1][c] + lp[2][c] + lp[3][c]);
}

// ---------------------------------------------------------------------------
// K2: pooled -> ratio -> num_tokens
// ---------------------------------------------------------------------------
__global__ __launch_bounds__(256) void k_pool(const float* __restrict__ pooled,
                                              const float* __restrict__ pw,
                                              const float* __restrict__ pb,
                                              int* __restrict__ ntok) {
  const int tid = threadIdx.x, wave = tid >> 6, lane = tid & 63;
  float a = 0.f;
  for (int c = tid; c < C; c += 256) a += pooled[c] * (1.f / N) * pw[c];
  a = wredsum(a);
  __shared__ float red[4];
  if (lane == 0) red[wave] = a;
  __syncthreads();
  if (tid == 0) {
    float d = red[0] + red[1] + red[2] + red[3] + pb[0];
    float ratio = 1.f / (1.f + expf(-d));
    int nt = (int)floorf(ratio * 64.f);
    nt = nt < 0 ? 0 : (nt > 64 ? 64 : nt);
    *ntok = nt;
  }
}

// ---------------------------------------------------------------------------
// K3 (MFMA, barrier-free): fused grouped conv1 + ReLU + scores GEMM.
// Per-wave DOUBLE-BUFFERED h (g&1) breaks the LDS WAR chain across groups;
// unroll 2 gives the scheduler both halves to interleave.
// ---------------------------------------------------------------------------
__global__ __launch_bounds__(256, 4) void k_cs(const short* __restrict__ xn,
                                               const short* __restrict__ w1p,
                                               const short* __restrict__ w2p,
                                               float* __restrict__ scores) {
  __shared__ __align__(16) short hs[4][2][16 * 64];
  const int tid = threadIdx.x, wave = tid >> 6, lane = tid & 63;
  const int l15 = lane & 15, g2 = lane >> 4;
  {  // zero both per-wave buffers (pad cols 48..63 must be non-NaN)
    uint* hz = (uint*)hs[wave];
    for (int i = lane; i < 1024; i += 64) hz[i] = 0u;
  }
  const int row0 = blockIdx.x * 64 + wave * 16;
  f32x4 acc[4];
#pragma unroll
  for (int t = 0; t < 4; ++t) acc[t] = (f32x4){0.f, 0.f, 0.f, 0.f};
  const short* xrow = xn + (size_t)(row0 + l15) * 768;
  const int lo8 = lane * 8;

  short8 bx0 = *(const short8*)(xrow + g2 * 8);
  short8 bx1 = *(const short8*)(xrow + 32 + g2 * 8);
#pragma unroll 2
  for (int g = 0; g < 16; ++g) {
    const int gn = (g < 15) ? g + 1 : 15;
    short8 nbx0 = *(const short8*)(xrow + gn * 48 + g2 * 8);
    short8 nbx1 = *(const short8*)(xrow + gn * 48 + 32 + g2 * 8);
    short* hw = hs[wave][g & 1];
    const short* w1g = w1p + g * 3072;
#pragma unroll
    for (int ot = 0; ot < 3; ++ot) {
      short8 a0 = *(const short8*)(w1g + (ot * 2 + 0) * 512 + lo8);
      short8 a1 = *(const short8*)(w1g + (ot * 2 + 1) * 512 + lo8);
      f32x4 h = (f32x4){0.f, 0.f, 0.f, 0.f};
      h = mfma16(a0, bx0, h);
      h = mfma16(a1, bx1, h);
      uint lo = (uint)f2bits(fmaxf(h[0], 0.f)) | ((uint)f2bits(fmaxf(h[1], 0.f)) << 16);
      uint hi = (uint)f2bits(fmaxf(h[2], 0.f)) | ((uint)f2bits(fmaxf(h[3], 0.f)) << 16);
      *(uint2*)&hw[swz(l15, ot * 16 + g2 * 4)] = make_uint2(lo, hi);
    }
    short8 hb0 = *(const short8*)&hw[swz(l15, g2 * 8)];
    short8 hb1 = *(const short8*)&hw[swz(l15, 32 + g2 * 8)];
    const short* w2g = w2p + g * 4096;
#pragma unroll
    for (int tt = 0; tt < 4; ++tt) {
      short8 a0 = *(const short8*)(w2g + (tt * 2 + 0) * 512 + lo8);
      short8 a1 = *(const short8*)(w2g + (tt * 2 + 1) * 512 + lo8);
      acc[tt] = mfma16(a0, hb0, acc[tt]);
      acc[tt] = mfma16(a1, hb1, acc[tt]);
    }
    bx0 = nbx0; bx1 = nbx1;
  }
#pragma unroll
  for (int tt = 0; tt < 4; ++tt)
#pragma unroll
    for (int r = 0; r < 4; ++r)
      scores[(size_t)(tt * 16 + g2 * 4 + r) * N + row0 + l15] = acc[tt][r];
}

// ---------------------------------------------------------------------------
// K4: per-(t, segment) online softmax partial stats
// ---------------------------------------------------------------------------
__global__ __launch_bounds__(256) void k_stats(const float* __restrict__ scores,
                                               float2* __restrict__ part) {
  const int t = blockIdx.x >> 3, s = blockIdx.x & 7;
  const float* row = scores + (size_t)t * N + s * 8192;
  float m = -1e30f, l = 0.f;
  for (int i = threadIdx.x; i < 8192; i += 256) {
    float v = row[i];
    if (v > m) { l = l * __expf(m - v) + 1.f; m = v; }
    else       { l += __expf(v - m); }
  }
#pragma unroll
  for (int o = 32; o > 0; o >>= 1) {
    float m2 = __shfl_xor(m, o, 64), l2 = __shfl_xor(l, o, 64);
    float M = fmaxf(m, m2);
    l = l * __expf(m - M) + l2 * __expf(m2 - M); m = M;
  }
  __shared__ float sm[4], sl[4];
  const int wave = threadIdx.x >> 6, lane = threadIdx.x & 63;
  if (lane == 0) { sm[wave] = m; sl[wave] = l; }
  __syncthreads();
  if (threadIdx.x == 0) {
    float M = sm[0], L = sl[0];
    for (int w = 1; w < 4; w++) { float M2 = fmaxf(M, sm[w]); L = L * __expf(M - M2) + sl[w] * __expf(sm[w] - M2); M = M2; }
    part[blockIdx.x] = make_float2(M, L);
  }
}

// ---------------------------------------------------------------------------
// K5: merge partials (per block, 64B read) + write sel fp32 AND selb bf16.
// ---------------------------------------------------------------------------
__global__ __launch_bounds__(256) void k_sel(const float* __restrict__ scores,
                                             const float2* __restrict__ part,
                                             const int* __restrict__ ntokp,
                                             float* __restrict__ sel,
                                             ushort* __restrict__ selb) {
  const int t = blockIdx.x >> 3, s = blockIdx.x & 7;
  float M = -1e30f, L = 0.f;
#pragma unroll
  for (int i = 0; i < 8; i++) {
    float2 p = part[t * 8 + i];
    float M2 = fmaxf(M, p.x);
    L = L * __expf(M - M2) + p.y * __expf(p.x - M2); M = M2;
  }
  const float li = 1.f / L;
  const bool on = t < *ntokp;
  const size_t base = (size_t)t * N + s * 8192;
  const float4* sp = (const float4*)(scores + base);
  float4* op = (float4*)(sel + base);
  uint2* ob = (uint2*)(selb + base);
#pragma unroll
  for (int it = 0; it < 8; ++it) {
    int idx = threadIdx.x + 256 * it;
    float4 v = sp[idx];
    float4 e;
    e.x = on ? __expf(v.x - M) * li : 0.f;
    e.y = on ? __expf(v.y - M) * li : 0.f;
    e.z = on ? __expf(v.z - M) * li : 0.f;
    e.w = on ? __expf(v.w - M) * li : 0.f;
    op[idx] = e;
    ob[idx] = make_uint2((uint)f2bits(e.x) | ((uint)f2bits(e.y) << 16),
                         (uint)f2bits(e.z) | ((uint)f2bits(e.w) << 16));
  }
}

// ---------------------------------------------------------------------------
// K7 (MFMA): out_part[nb][t][c]. Swapped conv operands (A=xn, B=wf) so the
// featT write is 3x ds_write_b64; LDS double-buffer ft[2] -> 1 barrier/iter;
// register prefetch of next-iter xn/selb (HBM latency off the critical path).
// ---------------------------------------------------------------------------
__global__ __launch_bounds__(512, 2) void k_og(const short* __restrict__ xn,
                                               const short* __restrict__ wfp,
                                               const short* __restrict__ selb,
                                               const int* __restrict__ ntokp,
                                               ushort* __restrict__ out_part) {
  __shared__ __align__(16) short ft[2][192 * 64];  // 48 KB
  const int tid = threadIdx.x, wave = tid >> 6, lane = tid & 63;
  const int l15 = lane & 15, g2 = lane >> 4;
  const int cb = blockIdx.y, nb = blockIdx.x;
  const int ntok = *ntokp;
  const int gq = wave >> 1, ntq = wave & 1;   // conv role
  const int tt = wave >> 1, chalf = wave & 1; // og role
  const bool act = (tt * 16) < ntok;
  // wf B-fragments (ns-invariant, in regs)
  short8 wb0[3], wb1[3];
  {
    const short* wb = wfp + (size_t)(cb * 4 + gq) * 3072 + lane * 8;
#pragma unroll
    for (int ot = 0; ot < 3; ++ot) {
      wb0[ot] = *(const short8*)(wb + (ot * 2 + 0) * 512);
      wb1[ot] = *(const short8*)(wb + (ot * 2 + 1) * 512);
    }
  }
  f32x4 acc[6];
#pragma unroll
  for (int k = 0; k < 6; ++k) acc[k] = (f32x4){0.f, 0.f, 0.f, 0.f};

  const short* xr0 = xn + (size_t)(nb * 512 + ntq * 16 + l15) * 768 + (cb * 4 + gq) * 48;
  const short* sr0 = selb + (size_t)(tt * 16 + l15) * N + nb * 512 + g2 * 8;

  short8 bx0 = *(const short8*)(xr0 + g2 * 8);
  short8 bx1 = *(const short8*)(xr0 + 32 + g2 * 8);
  short8 ps = {};
  short8 nx0 = bx0, nx1 = bx1, nps = ps;

  for (int ns = 0; ns <= 16; ++ns) {
    if (ns < 16) {
      // prefetch next-iter globals (consumed after the barrier below)
      const int nsn = (ns < 15) ? ns + 1 : 15;
      nx0 = *(const short8*)(xr0 + nsn * 24576 + g2 * 8);
      nx1 = *(const short8*)(xr0 + nsn * 24576 + 32 + g2 * 8);
      nps = *(const short8*)(sr0 + ns * 32);
      // conv: D[col=c(l15), row=n(g2*4+r)] -> ft[ns&1], contiguous uint2 write
      short* f = ft[ns & 1];
#pragma unroll
      for (int ot = 0; ot < 3; ++ot) {
        f32x4 d = (f32x4){0.f, 0.f, 0.f, 0.f};
        d = mfma16(bx0, wb0[ot], d);
        d = mfma16(bx1, wb1[ot], d);
        int c = gq * 48 + ot * 16 + l15;
        uint lo = (uint)f2bits(d[0]) | ((uint)f2bits(d[1]) << 16);
        uint hi = (uint)f2bits(d[2]) | ((uint)f2bits(d[3]) << 16);
        *(uint2*)&f[c * 64 + ((ntq * 16 + g2 * 4) ^ ((c & 7) << 3))] = make_uint2(lo, hi);
      }
    }
    if (ns >= 1 && act) {
      const short* f = ft[(ns - 1) & 1];
#pragma unroll
      for (int ct = 0; ct < 6; ++ct) {
        int c = (chalf * 6 + ct) * 16 + l15;
        short8 fb = *(const short8*)&f[c * 64 + ((g2 * 8) ^ ((c & 7) << 3))];
        acc[ct] = mfma16(ps, fb, acc[ct]);
      }
    }
    __syncthreads();
    bx0 = nx0; bx1 = nx1; ps = nps;
  }
#pragma unroll
  for (int ct = 0; ct < 6; ++ct)
#pragma unroll
    for (int r = 0; r < 4; ++r) {
      int t = tt * 16 + g2 * 4 + r;
      int c = cb * 192 + (chalf * 6 + ct) * 16 + l15;
      out_part[(size_t)nb * (64 * 768) + t * 768 + c] = f2bits(acc[ct][r]);
    }
}

// ---------------------------------------------------------------------------
// K8: fused reduce(128 nb partials) + final LayerNorm + mask. 64 blocks (one
// per t), 192 threads (4 c each), uint2 (4xbf16) loads.
// ---------------------------------------------------------------------------
__global__ __launch_bounds__(192) void k_fin(const ushort* __restrict__ out_part,
                                             const float* __restrict__ ng,
                                             const float* __restrict__ nb_,
                                             const int* __restrict__ ntokp,
                                             float* __restrict__ outp) {
  const int t = blockIdx.x, tid = threadIdx.x;
  const int wave = tid >> 6, lane = tid & 63;
  const int c4 = tid * 4;
  float4 s = make_float4(0.f, 0.f, 0.f, 0.f);
  const ushort* base = out_part + t * 768 + c4;
  for (int nbk = 0; nbk < 128; ++nbk) {
    uint2 v = *(const uint2*)(base + (size_t)nbk * 49152);
    s.x += bits2f((ushort)(v.x & 0xffff)); s.y += bits2f((ushort)(v.x >> 16));
    s.z += bits2f((ushort)(v.y & 0xffff)); s.w += bits2f((ushort)(v.y >> 16));
  }
  float ss = s.x + s.y + s.z + s.w;
  float qq = s.x * s.x + s.y * s.y + s.z * s.z + s.w * s.w;
  ss = wredsum(ss); qq = wredsum(qq);
  __shared__ float sm[3], sq[3];
  if (lane == 0) { sm[wave] = ss; sq[wave] = qq; }
  __syncthreads();
  const float S = sm[0] + sm[1] + sm[2], Q = sq[0] + sq[1] + sq[2];
  const float mu = S * (1.f / C);
  const float rs = rsqrtf(Q * (1.f / C) - mu * mu + 1e-5f);
  const bool on = t < *ntokp;
  float4 g = *(const float4*)(ng + c4), b = *(const float4*)(nb_ + c4);
  float4 y;
  y.x = on ? (s.x - mu) * rs * g.x + b.x : 0.f;
  y.y = on ? (s.y - mu) * rs * g.y + b.y : 0.f;
  y.z = on ? (s.z - mu) * rs * g.z + b.z : 0.f;
  y.w = on ? (s.w - mu) * rs * g.w + b.w : 0.f;
  *(float4*)(outp + t * 768 + c4) = y;
}

// ---------------------------------------------------------------------------
extern "C" void kernel_launch(void* const* d_in, const int* in_sizes, int n_in,
                              void* d_out, int out_size, void* d_ws, size_t ws_size,
                              hipStream_t stream) {
  const float* x  = (const float*)d_in[0];
  const float* tg = (const float*)d_in[1];
  const float* tb = (const float*)d_in[2];
  const float* w1 = (const float*)d_in[3];
  const float* w2 = (const float*)d_in[4];
  const float* wf = (const float*)d_in[5];
  const float* pw = (const float*)d_in[6];
  const float* pb = (const float*)d_in[7];
  const float* ng = (const float*)d_in[8];
  const float* nb = (const float*)d_in[9];

  char* ws = (char*)d_ws;
  float*  pooled = (float*)(ws + 0);          // 3,072 B
  float2* part   = (float2*)(ws + 4096);      // 4,096 B
  int*    ntok   = (int*)(ws + 8704);
  short*  w1p    = (short*)(ws + 16384);      //  98,304 B
  short*  w2p    = (short*)(ws + 114688);     // 131,072 B
  short*  wfp    = (short*)(ws + 245760);     //  98,304 B
  short*  xn     = (short*)(ws + 344064);     // 100,663,296 B -> ends 101,007,360
  float*  scores = (float*)(ws + 101007360);  // 16,777,216 B -> ends 117,784,576
  ushort* opart  = (ushort*)(ws + 101007360); // overlay on dead scores, 12,582,912 B
  ushort* selb   = (ushort*)(ws + 117784576); // 8,388,608 B -> ends 126,173,184

  float* sel  = (float*)d_out;
  float* outp = (float*)d_out + (size_t)T * N;

  (void)hipMemsetAsync(pooled, 0, C * sizeof(float), stream);

  k_wprep <<<640, 256, 0, stream>>>(w1, w2, wf, w1p, w2p, wfp);
  k_ln    <<<1024, 256, 0, stream>>>((const float4*)x, (const float4*)tg, (const float4*)tb,
                                     (uint2*)xn, pooled);
  k_pool  <<<1, 256, 0, stream>>>(pooled, pw, pb, ntok);
  k_cs    <<<1024, 256, 0, stream>>>(xn, w1p, w2p, scores);
  k_stats <<<512, 256, 0, stream>>>(scores, part);
  k_sel   <<<512, 256, 0, stream>>>(scores, part, ntok, sel, selb);
  k_og    <<<dim3(128, 4), 512, 0, stream>>>(xn, wfp, (const short*)selb, ntok, opart);
  k_fin   <<<64, 192, 0, stream>>>(opart, ng, nb, ntok, outp);
}